// Round 10
// baseline (211.331 us; speedup 1.0000x reference)
//
#include <hip/hip_runtime.h>
#include <math.h>

#define DD 128
#define NEG_SLOPE 0.2f
#define SOFT_EPS 1e-16f
#define CHUNK 4096    // edges per block in bucketing/histogram passes
#define RCAP 2560     // per-bucket rank-stash capacity (bucket ~2046 +- 45)
// bucket b = dst >> 6 (64 nodes); requires N <= 65536 (u16 srcs, NBF <= 1024)

typedef __attribute__((ext_vector_type(8))) short short8;
typedef __attribute__((ext_vector_type(4))) float float4v;
typedef __attribute__((ext_vector_type(2))) float f2;

__device__ __forceinline__ float lrelu(float v) {
    return v >= 0.f ? v : NEG_SLOPE * v;
}
__device__ __forceinline__ unsigned f2bf(float f) {
    unsigned u = __float_as_uint(f);
    return (u + 0x7FFFu + ((u >> 16) & 1u)) >> 16;
}
__device__ __forceinline__ unsigned pk(float a, float b) {
    return f2bf(a) | (f2bf(b) << 16);
}
__device__ __forceinline__ float bfx(unsigned p) {
    return __uint_as_float(p << 16);
}
__device__ __forceinline__ float bfy(unsigned p) {
    return __uint_as_float(p & 0xFFFF0000u);
}

// ---- K0 "pre": coarse histogram (chunk per block) + W->Wtf (blocks 0-7) ----
__global__ __launch_bounds__(256) void k_pre(
        const float* __restrict__ W, uint4* __restrict__ Wtf4,
        const int* __restrict__ ei, int* __restrict__ bktCnt,
        int E, int NBFr) {
    __shared__ int sh[1024];
    const int tid = threadIdx.x;
    for (int i = tid; i < 1024; i += 256) sh[i] = 0;
    __syncthreads();
    int base = blockIdx.x * CHUNK;
    int lim = min(CHUNK, E - base);
    const int* dsts = ei + E + base;
    int nv4 = lim >> 2;
    for (int i4 = tid; i4 < nv4; i4 += 256) {
        int4 d4 = *(const int4*)&dsts[i4 * 4];
        atomicAdd(&sh[d4.x >> 6], 1); atomicAdd(&sh[d4.y >> 6], 1);
        atomicAdd(&sh[d4.z >> 6], 1); atomicAdd(&sh[d4.w >> 6], 1);
    }
    for (int i = nv4 * 4 + tid; i < lim; i += 256)
        atomicAdd(&sh[dsts[i] >> 6], 1);

    // W -> bf16 B-fragment order (blocks 0..7)
    int idx = blockIdx.x * 256 + tid;
    if (idx < 2048) {
        int g = idx >> 6, l = idx & 63;
        int ct = g >> 2, c = g & 3;
        int quad = l >> 4, n = l & 15;
        int col = ct * 16 + n;
        int k0 = c * 32 + quad * 8;
        uint4 o;
        o.x = pk(W[(k0 + 0) * DD + col], W[(k0 + 1) * DD + col]);
        o.y = pk(W[(k0 + 2) * DD + col], W[(k0 + 3) * DD + col]);
        o.z = pk(W[(k0 + 4) * DD + col], W[(k0 + 5) * DD + col]);
        o.w = pk(W[(k0 + 6) * DD + col], W[(k0 + 7) * DD + col]);
        Wtf4[idx] = o;
    }
    __syncthreads();
    for (int i = tid; i < NBFr; i += 256) {
        int c = sh[i];
        if (c) atomicAdd(&bktCnt[i], c);
    }
}

// ---- K1 "main" fat kernel: blocks [0,gemmBlocks) = MFMA gemm + scores;
//      blocks [gemmBlocks, +eblocks) = coarse bucket scatter ----
__global__ __launch_bounds__(256) void k_main(
        const float* __restrict__ x, const uint4* __restrict__ Wtf4,
        const float* __restrict__ att_src, const float* __restrict__ att_dst,
        unsigned* __restrict__ h32, float* __restrict__ a_src,
        float* __restrict__ a_dst,
        const int* __restrict__ ei, const int* __restrict__ bktCnt,
        int* __restrict__ bktCur, int* __restrict__ bktBase,
        int* __restrict__ pairs,
        int N, int E, int NBFr, int ntiles, int gemmBlocks) {
    __shared__ float sx[64 * 132];   // gemm: x-stage + C scratch; bucket: ints
    const int tid = threadIdx.x;
    const int bid = blockIdx.x;

    if (bid < gemmBlocks) {
        // ================= GEMM role =================
        const int w = tid >> 6;
        const int l = tid & 63;
        const int quad = l >> 4, n = l & 15;
        const int t = bid * 4 + w;
        const bool tv = t < ntiles;

#pragma unroll
        for (int it = 0; it < 8; ++it) {
            int lin = it * 256 + tid;
            int row = lin >> 5, c4 = lin & 31;
            int grow = bid * 64 + row;
            float4 v = make_float4(0.f, 0.f, 0.f, 0.f);
            if (grow < N) v = *(const float4*)&x[(size_t)grow * DD + c4 * 4];
            *(float4*)&sx[row * 132 + c4 * 4] = v;
        }
        __syncthreads();

        short8 af[4];
        if (tv) {
#pragma unroll
            for (int c = 0; c < 4; ++c) {
                const float* p = &sx[(w * 16 + n) * 132 + c * 32 + quad * 8];
                float4 v0 = *(const float4*)p;
                float4 v1 = *(const float4*)(p + 4);
                uint4 u;
                u.x = pk(v0.x, v0.y); u.y = pk(v0.z, v0.w);
                u.z = pk(v1.x, v1.y); u.w = pk(v1.z, v1.w);
                af[c] = __builtin_bit_cast(short8, u);
            }
        }
        __syncthreads();

        float ps[4] = {0.f, 0.f, 0.f, 0.f};
        float pd[4] = {0.f, 0.f, 0.f, 0.f};
        if (tv) {
#pragma unroll
            for (int ct = 0; ct < 8; ++ct) {
                float4v acc = {0.f, 0.f, 0.f, 0.f};
#pragma unroll
                for (int c = 0; c < 4; ++c) {
                    short8 bfr = __builtin_bit_cast(short8,
                                                    Wtf4[(ct * 4 + c) * 64 + l]);
                    acc = __builtin_amdgcn_mfma_f32_16x16x32_bf16(af[c], bfr,
                                                                  acc, 0, 0, 0);
                }
                float asv = att_src[ct * 16 + n];
                float adv = att_dst[ct * 16 + n];
#pragma unroll
                for (int reg = 0; reg < 4; ++reg) {
                    float v = acc[reg];
                    ps[reg] += v * asv;
                    pd[reg] += v * adv;
                    sx[w * 2112 + (quad * 4 + reg) * 132 + ct * 16 + n] = v;
                }
            }
#pragma unroll
            for (int reg = 0; reg < 4; ++reg) {
#pragma unroll
                for (int o = 1; o < 16; o <<= 1) {
                    ps[reg] += __shfl_xor(ps[reg], o);
                    pd[reg] += __shfl_xor(pd[reg], o);
                }
            }
            if (n == 0) {
#pragma unroll
                for (int reg = 0; reg < 4; ++reg) {
                    int grow = t * 16 + quad * 4 + reg;
                    if (grow < N) { a_src[grow] = ps[reg]; a_dst[grow] = pd[reg]; }
                }
            }
        }
        __syncthreads();
        if (tv) {
#pragma unroll
            for (int s = 0; s < 4; ++s) {
                int row = s * 4 + quad;
                const float* p = &sx[w * 2112 + row * 132 + n * 8];
                float4 v0 = *(const float4*)p;
                float4 v1 = *(const float4*)(p + 4);
                uint4 o;
                o.x = pk(v0.x, v0.y); o.y = pk(v0.z, v0.w);
                o.z = pk(v1.x, v1.y); o.w = pk(v1.z, v1.w);
                int grow = t * 16 + row;
                if (grow < N) *(uint4*)&h32[(size_t)grow * 64 + n * 4] = o;
            }
        }
    } else {
        // ================= BUCKET role =================
        int* cnt   = (int*)sx;          // 1024
        int* gbase = cnt + 1024;        // 1024
        int* sm    = gbase + 1024;      // 256
        const int chunk = bid - gemmBlocks;
        for (int i = tid; i < 1024; i += 256) cnt[i] = 0;
        __syncthreads();
        int base = chunk * CHUNK;
        int lim = min(CHUNK, E - base);
        const int* dsts = ei + E + base;
        const int* srcp = ei + base;
        int nv4 = lim >> 2;
        for (int i4 = tid; i4 < nv4; i4 += 256) {
            int4 d4 = *(const int4*)&dsts[i4 * 4];
            atomicAdd(&cnt[d4.x >> 6], 1); atomicAdd(&cnt[d4.y >> 6], 1);
            atomicAdd(&cnt[d4.z >> 6], 1); atomicAdd(&cnt[d4.w >> 6], 1);
        }
        for (int i = nv4 * 4 + tid; i < lim; i += 256)
            atomicAdd(&cnt[dsts[i] >> 6], 1);
        __syncthreads();
        // exclusive scan of 4-padded global bucket counts (4 entries/thread)
        int vloc[4], s0 = 0;
#pragma unroll
        for (int j = 0; j < 4; ++j) {
            int e = tid * 4 + j;
            int bc = (e < NBFr) ? bktCnt[e] : 0;
            vloc[j] = (bc + 3) & ~3;
            s0 += vloc[j];
        }
        sm[tid] = s0;
        __syncthreads();
        for (int ofs = 1; ofs < 256; ofs <<= 1) {
            int xv = (tid >= ofs) ? sm[tid - ofs] : 0;
            __syncthreads();
            sm[tid] += xv;
            __syncthreads();
        }
        int run = sm[tid] - s0;
#pragma unroll
        for (int j = 0; j < 4; ++j) {
            int e = tid * 4 + j;
            if (e < NBFr) {
                if (chunk == 0) bktBase[e] = run;
                int myc = cnt[e];
                gbase[e] = myc ? run + atomicAdd(&bktCur[e], myc) : 0;
            }
            run += vloc[j];
        }
        __syncthreads();
        for (int i = tid; i < 1024; i += 256) cnt[i] = 0;
        __syncthreads();
        for (int i4 = tid; i4 < nv4; i4 += 256) {
            int4 s4 = *(const int4*)&srcp[i4 * 4];
            int4 d4 = *(const int4*)&dsts[i4 * 4];
            int b, r;
            b = d4.x >> 6; r = atomicAdd(&cnt[b], 1);
            pairs[gbase[b] + r] = s4.x | ((d4.x & 63) << 16);
            b = d4.y >> 6; r = atomicAdd(&cnt[b], 1);
            pairs[gbase[b] + r] = s4.y | ((d4.y & 63) << 16);
            b = d4.z >> 6; r = atomicAdd(&cnt[b], 1);
            pairs[gbase[b] + r] = s4.z | ((d4.z & 63) << 16);
            b = d4.w >> 6; r = atomicAdd(&cnt[b], 1);
            pairs[gbase[b] + r] = s4.w | ((d4.w & 63) << 16);
        }
        for (int i = nv4 * 4 + tid; i < lim; i += 256) {
            int s = srcp[i], d = dsts[i];
            int b = d >> 6;
            int r = atomicAdd(&cnt[b], 1);
            pairs[gbase[b] + r] = s | ((d & 63) << 16);
        }
    }
}

// ---- K2: fine grouping, one 256-thr block per 64-node bucket ----
__global__ __launch_bounds__(256) void k_group(
        const int* __restrict__ bktBase, const int* __restrict__ bktCnt,
        const int* __restrict__ pairs, int* __restrict__ off,
        unsigned short* __restrict__ degw, unsigned short* __restrict__ srcs,
        int N) {
    __shared__ int cnt[64];
    __shared__ int excl[64];
    __shared__ unsigned short rnk[RCAP];
    int b = blockIdx.x, t = threadIdx.x;
    int r0 = bktBase[b];
    int ne = bktCnt[b];
    if (t < 64) cnt[t] = 0;
    __syncthreads();
    int nv4 = ne >> 2;
    bool fits = (ne <= RCAP);
    if (fits) {
        for (int i4 = t; i4 < nv4; i4 += 256) {
            int4 p4 = *(const int4*)&pairs[r0 + i4 * 4];
            rnk[i4 * 4 + 0] = (unsigned short)atomicAdd(&cnt[p4.x >> 16], 1);
            rnk[i4 * 4 + 1] = (unsigned short)atomicAdd(&cnt[p4.y >> 16], 1);
            rnk[i4 * 4 + 2] = (unsigned short)atomicAdd(&cnt[p4.z >> 16], 1);
            rnk[i4 * 4 + 3] = (unsigned short)atomicAdd(&cnt[p4.w >> 16], 1);
        }
        for (int i = nv4 * 4 + t; i < ne; i += 256)
            rnk[i] = (unsigned short)atomicAdd(&cnt[pairs[r0 + i] >> 16], 1);
    } else {
        for (int i = t; i < ne; i += 256)
            atomicAdd(&cnt[pairs[r0 + i] >> 16], 1);
    }
    __syncthreads();
    int v = 0;
    if (t < 64) { v = cnt[t]; excl[t] = v; }
    __syncthreads();
    for (int ofs = 1; ofs < 64; ofs <<= 1) {
        int xv = 0;
        if (t < 64 && t >= ofs) xv = excl[t - ofs];
        __syncthreads();
        if (t < 64) excl[t] += xv;
        __syncthreads();
    }
    if (t < 64) {
        int me = excl[t] - v;
        excl[t] = me;
        int node = b * 64 + t;
        if (node < N) {
            off[node] = r0 + me;
            degw[node] = (unsigned short)v;
        }
    }
    __syncthreads();
    if (fits) {
        for (int i4 = t; i4 < nv4; i4 += 256) {
            int4 p4 = *(const int4*)&pairs[r0 + i4 * 4];
            srcs[r0 + excl[p4.x >> 16] + rnk[i4 * 4 + 0]] = (unsigned short)(p4.x & 0xFFFF);
            srcs[r0 + excl[p4.y >> 16] + rnk[i4 * 4 + 1]] = (unsigned short)(p4.y & 0xFFFF);
            srcs[r0 + excl[p4.z >> 16] + rnk[i4 * 4 + 2]] = (unsigned short)(p4.z & 0xFFFF);
            srcs[r0 + excl[p4.w >> 16] + rnk[i4 * 4 + 3]] = (unsigned short)(p4.w & 0xFFFF);
        }
        for (int i = nv4 * 4 + t; i < ne; i += 256) {
            int p = pairs[r0 + i];
            srcs[r0 + excl[p >> 16] + rnk[i]] = (unsigned short)(p & 0xFFFF);
        }
    } else {
        if (t < 64) cnt[t] = 0;
        __syncthreads();
        for (int i = t; i < ne; i += 256) {
            int p = pairs[r0 + i];
            int dl = p >> 16;
            int r = atomicAdd(&cnt[dl], 1);
            srcs[r0 + excl[dl] + r] = (unsigned short)(p & 0xFFFF);
        }
    }
}

// slow-path 8-wide gather (shfl-broadcast; only for rare deg>64 nodes)
#define GATHER8(msv, mexv, JJ)                                                 \
    {                                                                          \
        int s0 = __shfl(msv, (JJ) + 0), s1 = __shfl(msv, (JJ) + 1);            \
        int s2 = __shfl(msv, (JJ) + 2), s3 = __shfl(msv, (JJ) + 3);            \
        int s4 = __shfl(msv, (JJ) + 4), s5 = __shfl(msv, (JJ) + 5);            \
        int s6 = __shfl(msv, (JJ) + 6), s7 = __shfl(msv, (JJ) + 7);            \
        float c0 = __shfl(mexv, (JJ) + 0), c1 = __shfl(mexv, (JJ) + 1);        \
        float c2 = __shfl(mexv, (JJ) + 2), c3 = __shfl(mexv, (JJ) + 3);        \
        float c4 = __shfl(mexv, (JJ) + 4), c5 = __shfl(mexv, (JJ) + 5);        \
        float c6 = __shfl(mexv, (JJ) + 6), c7 = __shfl(mexv, (JJ) + 7);        \
        unsigned u0 = h32[(size_t)s0 * 64 + lane];                             \
        unsigned u1 = h32[(size_t)s1 * 64 + lane];                             \
        unsigned u2 = h32[(size_t)s2 * 64 + lane];                             \
        unsigned u3 = h32[(size_t)s3 * 64 + lane];                             \
        unsigned u4 = h32[(size_t)s4 * 64 + lane];                             \
        unsigned u5 = h32[(size_t)s5 * 64 + lane];                             \
        unsigned u6 = h32[(size_t)s6 * 64 + lane];                             \
        unsigned u7 = h32[(size_t)s7 * 64 + lane];                             \
        a0 += bfx(u0) * c0 + bfx(u1) * c1 + bfx(u2) * c2 + bfx(u3) * c3 +      \
              bfx(u4) * c4 + bfx(u5) * c5 + bfx(u6) * c6 + bfx(u7) * c7;       \
        a1 += bfy(u0) * c0 + bfy(u1) * c1 + bfy(u2) * c2 + bfy(u3) * c3 +      \
              bfy(u4) * c4 + bfy(u5) * c5 + bfy(u6) * c6 + bfy(u7) * c7;       \
    }

// fast-path batched gather: addresses/coefs from per-wave LDS broadcast
#define FETCH8(U, JJ)                                                          \
    {                                                                          \
        _Pragma("unroll") for (int j = 0; j < 8; ++j) {                        \
            unsigned mb = sA[swb + (JJ) + j];                                  \
            U[j] = h32[mb + (unsigned)lane];                                   \
        }                                                                      \
    }
#define CONSUME8(U, JJ)                                                        \
    {                                                                          \
        _Pragma("unroll") for (int j = 0; j < 8; ++j) {                        \
            float cj = sB[swb + (JJ) + j];                                     \
            f2 hv = {bfx(U[j]), bfy(U[j])};                                    \
            f2 cv = {cj, cj};                                                  \
            acc = __builtin_elementwise_fma(hv, cv, acc);                      \
        }                                                                      \
    }

// ---- K3: one wave per dst node ----
__global__ __launch_bounds__(256) void k_agg(
        const int* __restrict__ off, const unsigned short* __restrict__ degw,
        const unsigned short* __restrict__ srcs,
        const unsigned* __restrict__ h32,
        const float* __restrict__ a_src, const float* __restrict__ a_dst,
        float* __restrict__ out, int N) {
    __shared__ unsigned sA[4 * 64];
    __shared__ float sB[4 * 64];
    int node = (blockIdx.x * 256 + threadIdx.x) >> 6;
    int lane = threadIdx.x & 63;
    int swb = (threadIdx.x >> 6) * 64;
    if (node >= N) return;
    int r0 = off[node];
    int deg = degw[node];
    float adst = a_dst[node];
    float self_al = lrelu(a_src[node] + adst);
    unsigned uself = h32[(size_t)node * 64 + lane];
    float a0, a1, inv;

    if (deg <= 64) {
        int ms = 0;
        float als = -1e30f;
        if (lane < deg) {
            ms = srcs[r0 + lane];
            als = lrelu(a_src[ms] + adst);
        }
        float m = fmaxf(self_al, als);
#pragma unroll
        for (int o = 32; o; o >>= 1) m = fmaxf(m, __shfl_xor(m, o));
        float mex = (lane < deg) ? __expf(als - m) : 0.f;
        float t = mex;
#pragma unroll
        for (int o = 32; o; o >>= 1) t += __shfl_xor(t, o);
        float eself = __expf(self_al - m);
        inv = 1.f / (t + eself + SOFT_EPS);
        sA[swb + lane] = (lane < deg) ? ((unsigned)ms << 6) : 0u;
        sB[swb + lane] = mex;
        f2 acc = {bfx(uself) * eself, bfy(uself) * eself};
        int degp = (deg + 7) & ~7;
        int jj = 0;
        for (; jj + 16 <= degp; jj += 16) {
            unsigned uA[8], uB[8];
            FETCH8(uA, jj);
            FETCH8(uB, jj + 8);
            CONSUME8(uA, jj);
            CONSUME8(uB, jj + 8);
        }
        if (jj < degp) {
            unsigned uA[8];
            FETCH8(uA, jj);
            CONSUME8(uA, jj);
        }
        a0 = acc.x; a1 = acc.y;
    } else {
        float m = self_al;
        for (int j = lane; j < deg; j += 64) {
            int s = srcs[r0 + j];
            m = fmaxf(m, lrelu(a_src[s] + adst));
        }
#pragma unroll
        for (int o = 32; o; o >>= 1) m = fmaxf(m, __shfl_xor(m, o));
        float eself = __expf(self_al - m);
        a0 = bfx(uself) * eself; a1 = bfy(uself) * eself;
        float t = 0.f;
        for (int c = 0; c < deg; c += 64) {
            int my = c + lane;
            int ms = (my < deg) ? (int)srcs[r0 + my] : 0;
            float mex = (my < deg) ? __expf(lrelu(a_src[ms] + adst) - m) : 0.f;
            t += mex;
            int lim = min(64, deg - c);
            int jj = 0;
            for (; jj + 8 <= lim; jj += 8) GATHER8(ms, mex, jj);
            for (; jj < lim; ++jj) {
                int s = __shfl(ms, jj);
                float cc = __shfl(mex, jj);
                unsigned u = h32[(size_t)s * 64 + lane];
                a0 += bfx(u) * cc; a1 += bfy(u) * cc;
            }
        }
#pragma unroll
        for (int o = 32; o; o >>= 1) t += __shfl_xor(t, o);
        inv = 1.f / (t + eself + SOFT_EPS);
    }
    a0 *= inv; a1 *= inv;
    *(float2*)&out[(size_t)node * DD + lane * 2] = make_float2(a0, a1);
}

extern "C" void kernel_launch(void* const* d_in, const int* in_sizes, int n_in,
                              void* d_out, int out_size, void* d_ws, size_t ws_size,
                              hipStream_t stream) {
    const float* x       = (const float*)d_in[0];
    const int*   ei      = (const int*)d_in[1];
    const float* W       = (const float*)d_in[2];
    const float* att_src = (const float*)d_in[3];
    const float* att_dst = (const float*)d_in[4];
    float* out = (float*)d_out;

    const int N = in_sizes[0] / DD;      // 50000
    const int E = in_sizes[1] / 2;       // 1600000
    const int NBFr = (N + 63) >> 6;      // 782 fine buckets
    const int ntiles = (N + 15) >> 4;    // 3125

    // ws (u32 units): h32[N*64] | a_src[N] | a_dst[N] | off[N] | degw[N u16]
    //   | bktCnt[NBFr] | bktCur[NBFr] | bktBase[1024] | Wtf[8192]
    //   | pairs[E+4096] | srcs[(E+4096) u16]
    unsigned* h32     = (unsigned*)d_ws;
    float*    a_src   = (float*)(h32 + (size_t)N * 64);
    float*    a_dst   = a_src + N;
    int*      off     = (int*)(a_dst + N);
    unsigned short* degw = (unsigned short*)(off + N);
    int*      bktCnt  = (int*)(degw + ((N + 1) & ~1));
    int*      bktCur  = bktCnt + NBFr;
    int*      bktBase = bktCur + NBFr;
    uint4*    Wtf4    = (uint4*)(bktBase + 1024);
    int*      pairs   = (int*)(Wtf4 + 2048);
    unsigned short* srcs = (unsigned short*)(pairs + E + 4096);

    const int eblocks = (E + CHUNK - 1) / CHUNK;    // 391
    const int gemmBlocks = (ntiles + 3) / 4;        // 782

    hipMemsetAsync(bktCnt, 0, 2 * NBFr * sizeof(int), stream);
    k_pre<<<eblocks, 256, 0, stream>>>(W, Wtf4, ei, bktCnt, E, NBFr);
    k_main<<<gemmBlocks + eblocks, 256, 0, stream>>>(
        x, Wtf4, att_src, att_dst, h32, a_src, a_dst,
        ei, bktCnt, bktCur, bktBase, pairs, N, E, NBFr, ntiles, gemmBlocks);
    k_group<<<NBFr, 256, 0, stream>>>(bktBase, bktCnt, pairs, off, degw,
                                      srcs, N);
    k_agg<<<(N * 64 + 255) / 256, 256, 0, stream>>>(off, degw, srcs, h32,
                                                    a_src, a_dst, out, N);
}

// Round 11
// 178.866 us; speedup vs baseline: 1.1815x; 1.1815x over previous
//
#include <hip/hip_runtime.h>
#include <math.h>

#define DD 128
#define NEG_SLOPE 0.2f
#define SOFT_EPS 1e-16f
#define CHUNK 4096    // edges per block in bucketing pass
#define RCAP 9216     // per-bucket rank-stash capacity (bucket ~8192 +- 90)
#define BCAP 12288    // fixed per-bucket region capacity (>40 sigma margin)
// bucket b = dst >> 8 (256 nodes); requires N <= 65536 (u16 srcs)

typedef __attribute__((ext_vector_type(8))) short short8;
typedef __attribute__((ext_vector_type(4))) float float4v;
typedef __attribute__((ext_vector_type(2))) float f2;

__device__ __forceinline__ float lrelu(float v) {
    return v >= 0.f ? v : NEG_SLOPE * v;
}
__device__ __forceinline__ unsigned f2bf(float f) {
    unsigned u = __float_as_uint(f);
    return (u + 0x7FFFu + ((u >> 16) & 1u)) >> 16;
}
__device__ __forceinline__ unsigned pk(float a, float b) {
    return f2bf(a) | (f2bf(b) << 16);
}
__device__ __forceinline__ float bfx(unsigned p) {
    return __uint_as_float(p << 16);
}
__device__ __forceinline__ float bfy(unsigned p) {
    return __uint_as_float(p & 0xFFFF0000u);
}

// ---- K0: W -> Wtf (MFMA B-fragment order) + zero bktCur ----
__global__ __launch_bounds__(256) void k_wt(
        const float* __restrict__ W, uint4* __restrict__ Wtf4,
        int* __restrict__ bktCur, int nz) {
    int idx = blockIdx.x * 256 + threadIdx.x;    // 2048 threads
    if (idx < nz) bktCur[idx] = 0;
    if (idx >= 2048) return;
    int g = idx >> 6, l = idx & 63;
    int ct = g >> 2, c = g & 3;
    int quad = l >> 4, n = l & 15;
    int col = ct * 16 + n;
    int k0 = c * 32 + quad * 8;
    uint4 o;
    o.x = pk(W[(k0 + 0) * DD + col], W[(k0 + 1) * DD + col]);
    o.y = pk(W[(k0 + 2) * DD + col], W[(k0 + 3) * DD + col]);
    o.z = pk(W[(k0 + 4) * DD + col], W[(k0 + 5) * DD + col]);
    o.w = pk(W[(k0 + 6) * DD + col], W[(k0 + 7) * DD + col]);
    Wtf4[idx] = o;
}

// ---- K1: h = x @ W via MFMA (x staged in LDS) + fused node scores ----
// block 256 = 4 waves; wave w owns tile t = blockIdx*4+w (16 rows x 128 cols)
__global__ __launch_bounds__(256) void k_gemm(
        const float* __restrict__ x, const uint4* __restrict__ Wtf4,
        const float* __restrict__ att_src, const float* __restrict__ att_dst,
        unsigned* __restrict__ h32, float* __restrict__ a_src,
        float* __restrict__ a_dst, int N, int ntiles) {
    __shared__ float sx[64 * 132];   // 33.8 KB: x-stage, then C-tile scratch
    const int tid = threadIdx.x;
    const int w = tid >> 6;
    const int l = tid & 63;
    const int quad = l >> 4, n = l & 15;
    const int t = blockIdx.x * 4 + w;
    const bool tv = t < ntiles;

#pragma unroll
    for (int it = 0; it < 8; ++it) {
        int lin = it * 256 + tid;
        int row = lin >> 5, c4 = lin & 31;
        int grow = blockIdx.x * 64 + row;
        float4 v = make_float4(0.f, 0.f, 0.f, 0.f);
        if (grow < N) v = *(const float4*)&x[(size_t)grow * DD + c4 * 4];
        *(float4*)&sx[row * 132 + c4 * 4] = v;
    }
    __syncthreads();

    short8 af[4];
    if (tv) {
#pragma unroll
        for (int c = 0; c < 4; ++c) {
            const float* p = &sx[(w * 16 + n) * 132 + c * 32 + quad * 8];
            float4 v0 = *(const float4*)p;
            float4 v1 = *(const float4*)(p + 4);
            uint4 u;
            u.x = pk(v0.x, v0.y); u.y = pk(v0.z, v0.w);
            u.z = pk(v1.x, v1.y); u.w = pk(v1.z, v1.w);
            af[c] = __builtin_bit_cast(short8, u);
        }
    }
    __syncthreads();

    float ps[4] = {0.f, 0.f, 0.f, 0.f};
    float pd[4] = {0.f, 0.f, 0.f, 0.f};
    if (tv) {
#pragma unroll
        for (int ct = 0; ct < 8; ++ct) {
            float4v acc = {0.f, 0.f, 0.f, 0.f};
#pragma unroll
            for (int c = 0; c < 4; ++c) {
                short8 bfr = __builtin_bit_cast(short8,
                                                Wtf4[(ct * 4 + c) * 64 + l]);
                acc = __builtin_amdgcn_mfma_f32_16x16x32_bf16(af[c], bfr, acc,
                                                              0, 0, 0);
            }
            float asv = att_src[ct * 16 + n];
            float adv = att_dst[ct * 16 + n];
#pragma unroll
            for (int reg = 0; reg < 4; ++reg) {
                float v = acc[reg];
                ps[reg] += v * asv;
                pd[reg] += v * adv;
                sx[w * 2112 + (quad * 4 + reg) * 132 + ct * 16 + n] = v;
            }
        }
#pragma unroll
        for (int reg = 0; reg < 4; ++reg) {
#pragma unroll
            for (int o = 1; o < 16; o <<= 1) {
                ps[reg] += __shfl_xor(ps[reg], o);
                pd[reg] += __shfl_xor(pd[reg], o);
            }
        }
        if (n == 0) {
#pragma unroll
            for (int reg = 0; reg < 4; ++reg) {
                int grow = t * 16 + quad * 4 + reg;
                if (grow < N) { a_src[grow] = ps[reg]; a_dst[grow] = pd[reg]; }
            }
        }
    }
    __syncthreads();
    if (tv) {
#pragma unroll
        for (int s = 0; s < 4; ++s) {
            int row = s * 4 + quad;
            const float* p = &sx[w * 2112 + row * 132 + n * 8];
            float4 v0 = *(const float4*)p;
            float4 v1 = *(const float4*)(p + 4);
            uint4 o;
            o.x = pk(v0.x, v0.y); o.y = pk(v0.z, v0.w);
            o.z = pk(v1.x, v1.y); o.w = pk(v1.z, v1.w);
            int grow = t * 16 + row;
            if (grow < N) *(uint4*)&h32[(size_t)grow * 64 + n * 4] = o;
        }
    }
}

// ---- K2: coarse scatter into fixed-capacity bucket regions ----
// no global histogram/scan: region base = b*BCAP, cursor = bktCur[b]
__global__ __launch_bounds__(256) void k_bucket(
        const int* __restrict__ ei, int* __restrict__ bktCur,
        int* __restrict__ pairs, int E, int NB) {
    __shared__ int cnt[256];
    __shared__ int gbase[256];
    int t = threadIdx.x;
    cnt[t] = 0;
    __syncthreads();
    int base = blockIdx.x * CHUNK;
    int lim = min(CHUNK, E - base);
    const int* dsts = ei + E + base;
    const int* srcp = ei + base;
    int nv4 = lim >> 2;
    for (int i4 = t; i4 < nv4; i4 += 256) {
        int4 d4 = *(const int4*)&dsts[i4 * 4];
        atomicAdd(&cnt[d4.x >> 8], 1); atomicAdd(&cnt[d4.y >> 8], 1);
        atomicAdd(&cnt[d4.z >> 8], 1); atomicAdd(&cnt[d4.w >> 8], 1);
    }
    for (int i = nv4 * 4 + t; i < lim; i += 256)
        atomicAdd(&cnt[dsts[i] >> 8], 1);
    __syncthreads();
    int c = cnt[t];
    if (t < NB && c) gbase[t] = t * BCAP + atomicAdd(&bktCur[t], c);
    __syncthreads();
    cnt[t] = 0;
    __syncthreads();
    for (int i4 = t; i4 < nv4; i4 += 256) {
        int4 s4 = *(const int4*)&srcp[i4 * 4];
        int4 d4 = *(const int4*)&dsts[i4 * 4];
        int b, r;
        b = d4.x >> 8; r = atomicAdd(&cnt[b], 1);
        pairs[gbase[b] + r] = s4.x | ((d4.x & 255) << 16);
        b = d4.y >> 8; r = atomicAdd(&cnt[b], 1);
        pairs[gbase[b] + r] = s4.y | ((d4.y & 255) << 16);
        b = d4.z >> 8; r = atomicAdd(&cnt[b], 1);
        pairs[gbase[b] + r] = s4.z | ((d4.z & 255) << 16);
        b = d4.w >> 8; r = atomicAdd(&cnt[b], 1);
        pairs[gbase[b] + r] = s4.w | ((d4.w & 255) << 16);
    }
    for (int i = nv4 * 4 + t; i < lim; i += 256) {
        int s = srcp[i], d = dsts[i];
        int b = d >> 8;
        int r = atomicAdd(&cnt[b], 1);
        pairs[gbase[b] + r] = s | ((d & 255) << 16);
    }
}

// ---- K3: fine grouping (1024 thr/bucket); rank-stash, no phase-3 atomics
__global__ __launch_bounds__(1024) void k_group(
        const int* __restrict__ bktCur, const int* __restrict__ pairs,
        int* __restrict__ off, unsigned short* __restrict__ degw,
        unsigned short* __restrict__ srcs, int N) {
    __shared__ int cnt[256];
    __shared__ int excl[256];
    __shared__ unsigned short rnk[RCAP];
    int b = blockIdx.x, t = threadIdx.x;
    int r0 = b * BCAP;
    int ne = bktCur[b];
    if (t < 256) cnt[t] = 0;
    __syncthreads();
    int nv4 = ne >> 2;
    bool fits = (ne <= RCAP);
    if (fits) {
        for (int i4 = t; i4 < nv4; i4 += 1024) {
            int4 p4 = *(const int4*)&pairs[r0 + i4 * 4];
            rnk[i4 * 4 + 0] = (unsigned short)atomicAdd(&cnt[p4.x >> 16], 1);
            rnk[i4 * 4 + 1] = (unsigned short)atomicAdd(&cnt[p4.y >> 16], 1);
            rnk[i4 * 4 + 2] = (unsigned short)atomicAdd(&cnt[p4.z >> 16], 1);
            rnk[i4 * 4 + 3] = (unsigned short)atomicAdd(&cnt[p4.w >> 16], 1);
        }
        for (int i = nv4 * 4 + t; i < ne; i += 1024)
            rnk[i] = (unsigned short)atomicAdd(&cnt[pairs[r0 + i] >> 16], 1);
    } else {
        for (int i = t; i < ne; i += 1024)
            atomicAdd(&cnt[pairs[r0 + i] >> 16], 1);
    }
    __syncthreads();
    int v = 0;
    if (t < 256) { v = cnt[t]; excl[t] = v; }
    __syncthreads();
    for (int ofs = 1; ofs < 256; ofs <<= 1) {
        int xv = 0;
        if (t < 256 && t >= ofs) xv = excl[t - ofs];
        __syncthreads();
        if (t < 256) excl[t] += xv;
        __syncthreads();
    }
    if (t < 256) {
        int me = excl[t] - v;
        excl[t] = me;
        int node = b * 256 + t;
        if (node < N) {
            off[node] = r0 + me;
            degw[node] = (unsigned short)v;
        }
    }
    __syncthreads();
    if (fits) {
        for (int i4 = t; i4 < nv4; i4 += 1024) {
            int4 p4 = *(const int4*)&pairs[r0 + i4 * 4];
            srcs[r0 + excl[p4.x >> 16] + rnk[i4 * 4 + 0]] = (unsigned short)(p4.x & 0xFFFF);
            srcs[r0 + excl[p4.y >> 16] + rnk[i4 * 4 + 1]] = (unsigned short)(p4.y & 0xFFFF);
            srcs[r0 + excl[p4.z >> 16] + rnk[i4 * 4 + 2]] = (unsigned short)(p4.z & 0xFFFF);
            srcs[r0 + excl[p4.w >> 16] + rnk[i4 * 4 + 3]] = (unsigned short)(p4.w & 0xFFFF);
        }
        for (int i = nv4 * 4 + t; i < ne; i += 1024) {
            int p = pairs[r0 + i];
            srcs[r0 + excl[p >> 16] + rnk[i]] = (unsigned short)(p & 0xFFFF);
        }
    } else {
        if (t < 256) cnt[t] = 0;
        __syncthreads();
        for (int i = t; i < ne; i += 1024) {
            int p = pairs[r0 + i];
            int dl = p >> 16;
            int r = atomicAdd(&cnt[dl], 1);
            srcs[r0 + excl[dl] + r] = (unsigned short)(p & 0xFFFF);
        }
    }
}

// slow-path 8-wide gather (shfl-broadcast; only for rare deg>64 nodes)
#define GATHER8(msv, mexv, JJ)                                                 \
    {                                                                          \
        int s0 = __shfl(msv, (JJ) + 0), s1 = __shfl(msv, (JJ) + 1);            \
        int s2 = __shfl(msv, (JJ) + 2), s3 = __shfl(msv, (JJ) + 3);            \
        int s4 = __shfl(msv, (JJ) + 4), s5 = __shfl(msv, (JJ) + 5);            \
        int s6 = __shfl(msv, (JJ) + 6), s7 = __shfl(msv, (JJ) + 7);            \
        float c0 = __shfl(mexv, (JJ) + 0), c1 = __shfl(mexv, (JJ) + 1);        \
        float c2 = __shfl(mexv, (JJ) + 2), c3 = __shfl(mexv, (JJ) + 3);        \
        float c4 = __shfl(mexv, (JJ) + 4), c5 = __shfl(mexv, (JJ) + 5);        \
        float c6 = __shfl(mexv, (JJ) + 6), c7 = __shfl(mexv, (JJ) + 7);        \
        unsigned u0 = h32[(size_t)s0 * 64 + lane];                             \
        unsigned u1 = h32[(size_t)s1 * 64 + lane];                             \
        unsigned u2 = h32[(size_t)s2 * 64 + lane];                             \
        unsigned u3 = h32[(size_t)s3 * 64 + lane];                             \
        unsigned u4 = h32[(size_t)s4 * 64 + lane];                             \
        unsigned u5 = h32[(size_t)s5 * 64 + lane];                             \
        unsigned u6 = h32[(size_t)s6 * 64 + lane];                             \
        unsigned u7 = h32[(size_t)s7 * 64 + lane];                             \
        a0 += bfx(u0) * c0 + bfx(u1) * c1 + bfx(u2) * c2 + bfx(u3) * c3 +      \
              bfx(u4) * c4 + bfx(u5) * c5 + bfx(u6) * c6 + bfx(u7) * c7;       \
        a1 += bfy(u0) * c0 + bfy(u1) * c1 + bfy(u2) * c2 + bfy(u3) * c3 +      \
              bfy(u4) * c4 + bfy(u5) * c5 + bfy(u6) * c6 + bfy(u7) * c7;       \
    }

// fast-path batched gather: addresses/coefs from per-wave LDS broadcast
#define FETCH8(U, JJ)                                                          \
    {                                                                          \
        _Pragma("unroll") for (int j = 0; j < 8; ++j) {                        \
            unsigned mb = sA[swb + (JJ) + j];                                  \
            U[j] = h32[mb + (unsigned)lane];                                   \
        }                                                                      \
    }
#define CONSUME8(U, JJ)                                                        \
    {                                                                          \
        _Pragma("unroll") for (int j = 0; j < 8; ++j) {                        \
            float cj = sB[swb + (JJ) + j];                                     \
            f2 hv = {bfx(U[j]), bfy(U[j])};                                    \
            f2 cv = {cj, cj};                                                  \
            acc = __builtin_elementwise_fma(hv, cv, acc);                      \
        }                                                                      \
    }

// ---- K4: one wave per dst node ----
__global__ __launch_bounds__(256) void k_agg(
        const int* __restrict__ off, const unsigned short* __restrict__ degw,
        const unsigned short* __restrict__ srcs,
        const unsigned* __restrict__ h32,
        const float* __restrict__ a_src, const float* __restrict__ a_dst,
        float* __restrict__ out, int N) {
    __shared__ unsigned sA[4 * 64];
    __shared__ float sB[4 * 64];
    int node = (blockIdx.x * 256 + threadIdx.x) >> 6;
    int lane = threadIdx.x & 63;
    int swb = (threadIdx.x >> 6) * 64;
    if (node >= N) return;
    int r0 = off[node];
    int deg = degw[node];
    float adst = a_dst[node];
    float self_al = lrelu(a_src[node] + adst);
    unsigned uself = h32[(size_t)node * 64 + lane];
    float a0, a1, inv;

    if (deg <= 64) {
        int ms = 0;
        float als = -1e30f;
        if (lane < deg) {
            ms = srcs[r0 + lane];
            als = lrelu(a_src[ms] + adst);
        }
        float m = fmaxf(self_al, als);
#pragma unroll
        for (int o = 32; o; o >>= 1) m = fmaxf(m, __shfl_xor(m, o));
        float mex = (lane < deg) ? __expf(als - m) : 0.f;
        float t = mex;
#pragma unroll
        for (int o = 32; o; o >>= 1) t += __shfl_xor(t, o);
        float eself = __expf(self_al - m);
        inv = 1.f / (t + eself + SOFT_EPS);
        sA[swb + lane] = (lane < deg) ? ((unsigned)ms << 6) : 0u;
        sB[swb + lane] = mex;
        f2 acc = {bfx(uself) * eself, bfy(uself) * eself};
        int degp = (deg + 7) & ~7;
        int jj = 0;
        for (; jj + 16 <= degp; jj += 16) {
            unsigned uA[8], uB[8];
            FETCH8(uA, jj);
            FETCH8(uB, jj + 8);
            CONSUME8(uA, jj);
            CONSUME8(uB, jj + 8);
        }
        if (jj < degp) {
            unsigned uA[8];
            FETCH8(uA, jj);
            CONSUME8(uA, jj);
        }
        a0 = acc.x; a1 = acc.y;
    } else {
        float m = self_al;
        for (int j = lane; j < deg; j += 64) {
            int s = srcs[r0 + j];
            m = fmaxf(m, lrelu(a_src[s] + adst));
        }
#pragma unroll
        for (int o = 32; o; o >>= 1) m = fmaxf(m, __shfl_xor(m, o));
        float eself = __expf(self_al - m);
        a0 = bfx(uself) * eself; a1 = bfy(uself) * eself;
        float t = 0.f;
        for (int c = 0; c < deg; c += 64) {
            int my = c + lane;
            int ms = (my < deg) ? (int)srcs[r0 + my] : 0;
            float mex = (my < deg) ? __expf(lrelu(a_src[ms] + adst) - m) : 0.f;
            t += mex;
            int lim = min(64, deg - c);
            int jj = 0;
            for (; jj + 8 <= lim; jj += 8) GATHER8(ms, mex, jj);
            for (; jj < lim; ++jj) {
                int s = __shfl(ms, jj);
                float cc = __shfl(mex, jj);
                unsigned u = h32[(size_t)s * 64 + lane];
                a0 += bfx(u) * cc; a1 += bfy(u) * cc;
            }
        }
#pragma unroll
        for (int o = 32; o; o >>= 1) t += __shfl_xor(t, o);
        inv = 1.f / (t + eself + SOFT_EPS);
    }
    a0 *= inv; a1 *= inv;
    *(float2*)&out[(size_t)node * DD + lane * 2] = make_float2(a0, a1);
}

extern "C" void kernel_launch(void* const* d_in, const int* in_sizes, int n_in,
                              void* d_out, int out_size, void* d_ws, size_t ws_size,
                              hipStream_t stream) {
    const float* x       = (const float*)d_in[0];
    const int*   ei      = (const int*)d_in[1];
    const float* W       = (const float*)d_in[2];
    const float* att_src = (const float*)d_in[3];
    const float* att_dst = (const float*)d_in[4];
    float* out = (float*)d_out;

    const int N = in_sizes[0] / DD;      // 50000
    const int E = in_sizes[1] / 2;       // 1600000
    const int NB = (N + 255) >> 8;       // 196
    const int ntiles = (N + 15) >> 4;    // 3125

    // ws (u32 units): h32[N*64] | a_src[N] | a_dst[N] | off[N] | degw[N u16]
    //   | bktCur[NB] | Wtf[8192] | pairs[NB*BCAP] | srcs[NB*BCAP u16]  (~30 MB)
    unsigned* h32     = (unsigned*)d_ws;
    float*    a_src   = (float*)(h32 + (size_t)N * 64);
    float*    a_dst   = a_src + N;
    int*      off     = (int*)(a_dst + N);
    unsigned short* degw = (unsigned short*)(off + N);
    int*      bktCur  = (int*)(degw + ((N + 1) & ~1));
    uint4*    Wtf4    = (uint4*)(bktCur + NB);
    int*      pairs   = (int*)(Wtf4 + 2048);
    unsigned short* srcs = (unsigned short*)(pairs + (size_t)NB * BCAP);

    const int eblocks = (E + CHUNK - 1) / CHUNK;    // 391
    const int gblocks = (ntiles + 3) / 4;           // 782

    k_wt<<<8, 256, 0, stream>>>(W, Wtf4, bktCur, NB);
    k_gemm<<<gblocks, 256, 0, stream>>>(x, Wtf4, att_src, att_dst,
                                        h32, a_src, a_dst, N, ntiles);
    k_bucket<<<eblocks, 256, 0, stream>>>(ei, bktCur, pairs, E, NB);
    k_group<<<NB, 1024, 0, stream>>>(bktCur, pairs, off, degw, srcs, N);
    k_agg<<<(N * 64 + 255) / 256, 256, 0, stream>>>(off, degw, srcs, h32,
                                                    a_src, a_dst, out, N);
}